// Round 3
// baseline (350.177 us; speedup 1.0000x reference)
//
#include <hip/hip_runtime.h>

typedef unsigned short ushort_t;
typedef unsigned int uint32;
typedef __attribute__((ext_vector_type(8))) short short8;
typedef __attribute__((ext_vector_type(4))) float f32x4;
typedef __attribute__((ext_vector_type(2))) uint32 u32x2;

#define LDS_LOAD16(gptr, lptr)                                                             \
  __builtin_amdgcn_global_load_lds((const __attribute__((address_space(1))) uint32*)(gptr),\
                                   (__attribute__((address_space(3))) uint32*)(lptr),      \
                                   16, 0, 0)

__device__ __forceinline__ ushort_t f2b(float f) {
  uint32 u = __builtin_bit_cast(uint32, f);
  u += 0x7fffu + ((u >> 16) & 1u);   // RNE
  return (ushort_t)(u >> 16);
}
__device__ __forceinline__ uint32 pk2(float a, float b) {
  return (uint32)f2b(a) | ((uint32)f2b(b) << 16);
}

constexpr size_t E = (size_t)2048 * 2048;

// ---------------- fused fp32 -> bf16 convert (all 5 tensors) ----------------
__global__ __launch_bounds__(256) void k_cvt5(const float* __restrict__ a0, const float* __restrict__ a1,
                                              const float* __restrict__ a2, const float* __restrict__ a3,
                                              const float* __restrict__ a4, ushort_t* __restrict__ out) {
  const float* srcs[5] = {a0, a1, a2, a3, a4};
  const float* s = srcs[blockIdx.y];
  size_t i = ((size_t)blockIdx.x * 256 + threadIdx.x) * 4;
  float4 v = *(const float4*)(s + i);
  ushort4 o;
  o.x = f2b(v.x); o.y = f2b(v.y); o.z = f2b(v.z); o.w = f2b(v.w);
  *(ushort4*)(out + (size_t)blockIdx.y * E + i) = o;
}

// ===================== 3-buffer BK=32 rotating GEMM pipeline =====================
// Per body t: stage tile t+2 into buf[(t+2)%3]; ds_read+MFMA buf[t%3]; vmcnt(4); s_barrier.
// Race-free: stage target's previous reads finished before body t-1's closing barrier.
// Counted vmcnt (never 0 in steady state) keeps 4-8 loads in flight across barriers (T4).
// Swizzle: slot = chunk ^ ((row>>1)&3) -> 16 rows hit 8 distinct bank-starts (2-way = free).

#define SWZ3(r) (((r) >> 1) & 3)

#define STG32(srcA, srcB, dA, dB, ktile)                                        \
  do {                                                                          \
    const int koff_ = (ktile) * 32;                                             \
    _Pragma("unroll") for (int j2_ = 0; j2_ < 2; ++j2_) {                       \
      int c_ = tid + 256 * j2_;                                                 \
      int r_ = c_ >> 2, p_ = c_ & 3;                                            \
      int sc_ = (p_ ^ SWZ3(r_)) * 8;                                            \
      LDS_LOAD16((srcA) + (row0 + r_) * 2048 + koff_ + sc_, &(dA)[c_ * 8]);     \
      LDS_LOAD16((srcB) + (col0 + r_) * 2048 + koff_ + sc_, &(dB)[c_ * 8]);     \
    }                                                                           \
  } while (0)

// ---------------- fused QKV GEMM-BT, fused RoPE epilogue ----------------
// z=0 -> Qm (rope + 1/sqrt(dh) scale), z=1 -> Km (rope), z=2 -> Vt (transposed write)
__global__ __launch_bounds__(256, 3) void k_gemm_qkv(const ushort_t* __restrict__ A,
                                                     const ushort_t* __restrict__ B0,
                                                     const ushort_t* __restrict__ B1,
                                                     const ushort_t* __restrict__ B2,
                                                     ushort_t* __restrict__ Qm,
                                                     ushort_t* __restrict__ Km,
                                                     ushort_t* __restrict__ Vt,
                                                     const int* __restrict__ pos) {
  __shared__ ushort_t As[3][128 * 32];
  __shared__ ushort_t Bs[3][128 * 32];
  const int tid = threadIdx.x;
  const int lane = tid & 63, wave = tid >> 6;
  const int quad = lane >> 4, l16 = lane & 15;
  const int wm = wave >> 1, wn = wave & 1;
  const int z = blockIdx.z;
  const ushort_t* Bp = (z == 0) ? B0 : (z == 1) ? B1 : B2;
  const size_t row0 = (size_t)blockIdx.y * 128, col0 = (size_t)blockIdx.x * 128;

  int g[4];
#pragma unroll
  for (int j = 0; j < 4; ++j) g[j] = (j & 1) + ((j >> 1) << 2) + wn * 2;  // {0,1,4,5}/{2,3,6,7}

  f32x4 zero = {0.f, 0.f, 0.f, 0.f};
  f32x4 acc[4][4];
#pragma unroll
  for (int i = 0; i < 4; ++i)
#pragma unroll
    for (int j = 0; j < 4; ++j) acc[i][j] = zero;

#define QKV_FRAGS(CUR)                                                          \
    short8 a_[4], b_[4];                                                        \
    _Pragma("unroll") for (int i_ = 0; i_ < 4; ++i_) {                          \
      int ra_ = wm * 64 + i_ * 16 + l16;                                        \
      a_[i_] = *(const short8*)&As[CUR][(ra_ * 4 + (quad ^ SWZ3(ra_))) * 8];    \
    }                                                                           \
    _Pragma("unroll") for (int j_ = 0; j_ < 4; ++j_) {                          \
      int rb_ = g[j_] * 16 + l16;                                               \
      b_[j_] = *(const short8*)&Bs[CUR][(rb_ * 4 + (quad ^ SWZ3(rb_))) * 8];    \
    }                                                                           \
    _Pragma("unroll") for (int i_ = 0; i_ < 4; ++i_)                            \
      _Pragma("unroll") for (int j_ = 0; j_ < 4; ++j_)                          \
        acc[i_][j_] = __builtin_amdgcn_mfma_f32_16x16x32_bf16(a_[i_], b_[j_], acc[i_][j_], 0, 0, 0);

#define QKV_BODY(T, CUR, STG, SEN, VM)                                          \
  do {                                                                          \
    if (SEN) STG32(A, Bp, As[STG], Bs[STG], (T) + 2);                           \
    QKV_FRAGS(CUR)                                                              \
    asm volatile("s_waitcnt " VM ::: "memory");                                 \
    __builtin_amdgcn_s_barrier();                                               \
  } while (0)

  // prologue: tiles 0,1 in flight; retire tile 0, keep tile 1 pending
  STG32(A, Bp, As[0], Bs[0], 0);
  STG32(A, Bp, As[1], Bs[1], 1);
  asm volatile("s_waitcnt vmcnt(4)" ::: "memory");
  __builtin_amdgcn_s_barrier();

  for (int tt = 0; tt < 60; tt += 3) {
    QKV_BODY(tt + 0, 0, 2, 1, "vmcnt(4)");
    QKV_BODY(tt + 1, 1, 0, 1, "vmcnt(4)");
    QKV_BODY(tt + 2, 2, 1, 1, "vmcnt(4)");
  }
  QKV_BODY(60, 0, 2, 1, "vmcnt(4)");
  QKV_BODY(61, 1, 0, 1, "vmcnt(4)");   // stages tile 63 into buf 0
  QKV_BODY(62, 2, 1, 0, "vmcnt(0)");   // no stage left; retire tile 63
  { QKV_FRAGS(0) }                     // t=63, no wait/barrier needed

  if (z < 2) {
    ushort_t* C = z ? Km : Qm;
    const float mul = z ? 1.0f : 0.08838834764831845f;  // fold 1/sqrt(128) into Q
#pragma unroll
    for (int i = 0; i < 4; ++i)
#pragma unroll
      for (int r = 0; r < 4; ++r) {
        size_t row = row0 + wm * 64 + i * 16 + quad * 4 + r;
        float pt = (float)pos[row];
        size_t rowoff = row * 2048 + col0;
#pragma unroll
        for (int j = 0; j < 2; ++j) {
          int f = g[j] * 16 + l16;   // f in [0,64)
          float ang = pt * __expf(-0.14391156831212787f * (float)f);
          float sn, cs;
          __sincosf(ang, &sn, &cs);
          cs *= mul; sn *= mul;
          float q0 = acc[i][j][r], q1 = acc[i][j + 2][r];
          C[rowoff + f]      = f2b(q0 * cs - q1 * sn);
          C[rowoff + f + 64] = f2b(q1 * cs + q0 * sn);
        }
      }
  } else {
#pragma unroll
    for (int i = 0; i < 4; ++i)
#pragma unroll
      for (int j = 0; j < 4; ++j) {
        size_t col = col0 + g[j] * 16 + l16;
        size_t rowb = row0 + wm * 64 + i * 16 + quad * 4;
        ushort4 ov;
        ov.x = f2b(acc[i][j][0]); ov.y = f2b(acc[i][j][1]);
        ov.z = f2b(acc[i][j][2]); ov.w = f2b(acc[i][j][3]);
        *(ushort4*)&Vt[col * 2048 + rowb] = ov;
      }
  }
}

// ---------------- flash attention: 32 q-rows/block, key-split waves ----------------
// Grid 1024 = 16 heads x 64 q-tiles, XCD-clustered (each XCD sees only 2 heads' K/V -> L2-fit).
// Halved q-tile (vs R0's 64) halves oacc to [2][8]=64 regs; QK restructured kg-outer so the
// live set (~124 unified regs) fits __launch_bounds__(256,4) -> 4 blocks/CU = 16 waves/CU,
// 2x the latency-hiding TLP of the old 2-block/grid-limited version.
__global__ __launch_bounds__(256, 4) void k_attn(const ushort_t* __restrict__ Q,
                                                 const ushort_t* __restrict__ Kg,
                                                 const ushort_t* __restrict__ Vt,
                                                 ushort_t* __restrict__ O) {
  __shared__ uint32 smem[8448 + 128];   // 33.5 KB: Qs 8K + Pbf 10K (epilogue alias Rbuf 33K) + Lred .5K
  ushort_t* Qs  = (ushort_t*)smem;      // 32 x 128 bf16, swizzled: chunk c at c ^ (r&15)
  uint32*   Pbf = smem + 2048;          // 4 waves x 32 rows x 20 dwords (80 B stride)
  float*    Lred = (float*)(smem + 8448);  // [wave][qg][l16]
  float*    Rbuf = (float*)smem;        // epilogue alias: [wave][16][132] = 8448 dw

  const int tid = threadIdx.x;
  const int lane = tid & 63, wave = tid >> 6;
  const int quad = lane >> 4, l16 = lane & 15;
  const int bid = blockIdx.x;
  const int t = bid >> 3;
  const int head = ((bid & 7) << 1) + (t >> 6);
  const int qt = t & 63;

#pragma unroll
  for (int j = 0; j < 2; ++j) {
    int s = tid + 256 * j;
    int r = s >> 4, p = s & 15;
    LDS_LOAD16(Q + (size_t)(qt * 32 + r) * 2048 + head * 128 + ((p ^ (r & 15)) * 8), &Qs[s * 8]);
  }
  __syncthreads();

  f32x4 zero = {0.f, 0.f, 0.f, 0.f};
  f32x4 oacc[2][8];
#pragma unroll
  for (int qg = 0; qg < 2; ++qg)
#pragma unroll
    for (int ns = 0; ns < 8; ++ns) oacc[qg][ns] = zero;
  float l_acc[2] = {0.f, 0.f};

  const ushort_t* Kbase = Kg + (size_t)head * 128;
  const ushort_t* Vbase = Vt + (size_t)head * 128 * 2048;
  uint32* pw = Pbf + wave * 640;

  for (int it = 0; it < 16; ++it) {
    const int kb = it * 128 + wave * 32;

#pragma unroll
    for (int kg = 0; kg < 2; ++kg) {
      short8 kf[4];
#pragma unroll
      for (int kk = 0; kk < 4; ++kk)
        kf[kk] = *(const short8*)&Kbase[(size_t)(kb + kg * 16 + l16) * 2048 + kk * 32 + quad * 8];
#pragma unroll
      for (int qg = 0; qg < 2; ++qg) {
        f32x4 s = zero;
#pragma unroll
        for (int kk = 0; kk < 4; ++kk) {
          short8 qa = *(const short8*)&Qs[((qg * 16 + l16) * 16 + ((kk * 4 + quad) ^ l16)) * 8];
          s = __builtin_amdgcn_mfma_f32_16x16x32_bf16(kf[kk], qa, s, 0, 0, 0);
        }
        float p0 = __expf(s[0]), p1 = __expf(s[1]);
        float p2 = __expf(s[2]), p3 = __expf(s[3]);
        l_acc[qg] += (p0 + p1) + (p2 + p3);
        // store S^T C-layout fragment into [qrow][key] (keys kg*16 + quad*4..+3)
        u32x2 w;
        w[0] = pk2(p0, p1); w[1] = pk2(p2, p3);
        *(u32x2*)&pw[(qg * 16 + l16) * 20 + kg * 8 + quad * 2] = w;
      }
    }

    short8 pb[2];
#pragma unroll
    for (int qg = 0; qg < 2; ++qg)
      pb[qg] = *(const short8*)&pw[(qg * 16 + l16) * 20 + quad * 4];  // B-op: [n=qrow][k=key]

#pragma unroll
    for (int ns = 0; ns < 8; ++ns) {
      const short8 vf = *(const short8*)&Vbase[(size_t)(ns * 16 + l16) * 2048 + kb + quad * 8];
#pragma unroll
      for (int qg = 0; qg < 2; ++qg)
        oacc[qg][ns] = __builtin_amdgcn_mfma_f32_16x16x32_bf16(vf, pb[qg], oacc[qg][ns], 0, 0, 0);
    }
  }

#pragma unroll
  for (int qg = 0; qg < 2; ++qg) {
    float l = l_acc[qg];
    l += __shfl_xor(l, 16, 64);
    l += __shfl_xor(l, 32, 64);
    l_acc[qg] = l;
  }
  if (quad == 0) {
#pragma unroll
    for (int qg = 0; qg < 2; ++qg) Lred[wave * 32 + qg * 16 + l16] = l_acc[qg];
  }

  const int tq = tid >> 4;
  const int td = (tid & 15) * 8;
  for (int qg = 0; qg < 2; ++qg) {
    __syncthreads();   // pass 0: Qs/Pbf dead, Lred visible; later: Rbuf free
#pragma unroll
    for (int ns = 0; ns < 8; ++ns)
      *(f32x4*)&Rbuf[(wave * 16 + l16) * 132 + ns * 16 + quad * 4] = oacc[qg][ns];
    __syncthreads();
    float lt = Lred[qg * 16 + tq] + Lred[32 + qg * 16 + tq] +
               Lred[64 + qg * 16 + tq] + Lred[96 + qg * 16 + tq];
    float inv = 1.0f / lt;
    f32x4 sA = zero, sB = zero;
#pragma unroll
    for (int w = 0; w < 4; ++w) {
      sA += *(const f32x4*)&Rbuf[(w * 16 + tq) * 132 + td];
      sB += *(const f32x4*)&Rbuf[(w * 16 + tq) * 132 + td + 4];
    }
    ushort4 o1, o2;
    o1.x = f2b(sA[0] * inv); o1.y = f2b(sA[1] * inv);
    o1.z = f2b(sA[2] * inv); o1.w = f2b(sA[3] * inv);
    o2.x = f2b(sB[0] * inv); o2.y = f2b(sB[1] * inv);
    o2.z = f2b(sB[2] * inv); o2.w = f2b(sB[3] * inv);
    size_t orow = (size_t)(qt * 32 + qg * 16 + tq) * 2048 + head * 128 + td;
    *(ushort4*)&O[orow] = o1;
    *(ushort4*)&O[orow + 4] = o2;
  }
}

// ---------------- Wo GEMM-BT, split-K=2: 128x128 tile, 3-buffer BK=32 pipeline ----------------
// grid (16,16,2): z selects K-half [z*1024, z*1024+1024). Partials to P[z*E + ...].
__global__ __launch_bounds__(256, 3) void k_gemm_wo_sk(const ushort_t* __restrict__ A,
                                                       const ushort_t* __restrict__ B,
                                                       float* __restrict__ P) {
  __shared__ ushort_t As[3][128 * 32];
  __shared__ ushort_t Bs[3][128 * 32];
  const int tid = threadIdx.x;
  const int lane = tid & 63, wave = tid >> 6;
  const int quad = lane >> 4, l16 = lane & 15;
  const int wm = wave >> 1, wn = wave & 1;
  const size_t row0 = (size_t)blockIdx.y * 128, col0 = (size_t)blockIdx.x * 128;
  const int k0 = blockIdx.z * 1024;
  float* Pz = P + (size_t)blockIdx.z * E;
  const ushort_t* Ak = A + k0;
  const ushort_t* Bk = B + k0;

  f32x4 zero = {0.f, 0.f, 0.f, 0.f};
  f32x4 acc[4][4];
#pragma unroll
  for (int i = 0; i < 4; ++i)
#pragma unroll
    for (int j = 0; j < 4; ++j) acc[i][j] = zero;

#define WO_FRAGS(CUR)                                                           \
    short8 a_[4], b_[4];                                                        \
    _Pragma("unroll") for (int i_ = 0; i_ < 4; ++i_) {                          \
      int ra_ = wm * 64 + i_ * 16 + l16;                                        \
      a_[i_] = *(const short8*)&As[CUR][(ra_ * 4 + (quad ^ SWZ3(ra_))) * 8];    \
    }                                                                           \
    _Pragma("unroll") for (int j_ = 0; j_ < 4; ++j_) {                          \
      int rb_ = wn * 64 + j_ * 16 + l16;                                        \
      b_[j_] = *(const short8*)&Bs[CUR][(rb_ * 4 + (quad ^ SWZ3(rb_))) * 8];    \
    }                                                                           \
    _Pragma("unroll") for (int i_ = 0; i_ < 4; ++i_)                            \
      _Pragma("unroll") for (int j_ = 0; j_ < 4; ++j_)                          \
        acc[i_][j_] = __builtin_amdgcn_mfma_f32_16x16x32_bf16(a_[i_], b_[j_], acc[i_][j_], 0, 0, 0);

#define WO_BODY(T, CUR, STG, SEN, VM)                                           \
  do {                                                                          \
    if (SEN) STG32(Ak, Bk, As[STG], Bs[STG], (T) + 2);                          \
    WO_FRAGS(CUR)                                                               \
    asm volatile("s_waitcnt " VM ::: "memory");                                 \
    __builtin_amdgcn_s_barrier();                                               \
  } while (0)

  STG32(Ak, Bk, As[0], Bs[0], 0);
  STG32(Ak, Bk, As[1], Bs[1], 1);
  asm volatile("s_waitcnt vmcnt(4)" ::: "memory");
  __builtin_amdgcn_s_barrier();

  for (int tt = 0; tt < 27; tt += 3) {
    WO_BODY(tt + 0, 0, 2, 1, "vmcnt(4)");
    WO_BODY(tt + 1, 1, 0, 1, "vmcnt(4)");
    WO_BODY(tt + 2, 2, 1, 1, "vmcnt(4)");
  }
  WO_BODY(27, 0, 2, 1, "vmcnt(4)");
  WO_BODY(28, 1, 0, 1, "vmcnt(4)");
  WO_BODY(29, 2, 1, 1, "vmcnt(4)");    // stages tile 31 into buf 1
  WO_BODY(30, 0, 2, 0, "vmcnt(0)");    // no stage left; retire tile 31
  { WO_FRAGS(1) }                      // t=31, no wait/barrier needed

#pragma unroll
  for (int i = 0; i < 4; ++i)
#pragma unroll
    for (int j = 0; j < 4; ++j)
#pragma unroll
      for (int r = 0; r < 4; ++r) {
        size_t row = row0 + wm * 64 + i * 16 + quad * 4 + r;
        size_t col = col0 + wn * 64 + j * 16 + l16;
        Pz[row * 2048 + col] = acc[i][j][r];
      }
}

// ---------------- split-K reduce: out = P0 + P1 (fp32) ----------------
__global__ __launch_bounds__(256) void k_red(const float* __restrict__ P, float* __restrict__ out) {
  size_t i = ((size_t)blockIdx.x * 256 + threadIdx.x) * 4;
  f32x4 a = *(const f32x4*)(P + i);
  f32x4 b = *(const f32x4*)(P + E + i);
  *(f32x4*)(out + i) = a + b;
}

extern "C" void kernel_launch(void* const* d_in, const int* in_sizes, int n_in,
                              void* d_out, int out_size, void* d_ws, size_t ws_size,
                              hipStream_t stream) {
  const float* X  = (const float*)d_in[0];
  const float* wq = (const float*)d_in[1];
  const float* wk = (const float*)d_in[2];
  const float* wv = (const float*)d_in[3];
  const float* wo = (const float*)d_in[4];
  const int*  pos = (const int*)d_in[5];
  float* out = (float*)d_out;

  if (ws_size < 9 * E * sizeof(ushort_t)) return;  // need 72 MB scratch

  ushort_t* Xb  = (ushort_t*)d_ws;
  ushort_t* Wqb = Xb + E;
  ushort_t* Wkb = Xb + 2 * E;
  ushort_t* Wvb = Xb + 3 * E;
  ushort_t* Wob = Xb + 4 * E;
  ushort_t* Qm  = Xb + 5 * E;
  ushort_t* Km  = Xb + 6 * E;
  ushort_t* Vtm = Xb + 7 * E;
  ushort_t* Om  = Xb + 8 * E;
  // After k_attn, Xb..Wvb (4E ushorts = 32 MB) are dead: reuse as 2x fp32 partial planes.
  float* Pf = (float*)Xb;   // P0 = [0,E) floats, P1 = [E,2E) floats

  dim3 b256(256);
  k_cvt5<<<dim3(4096, 5), b256, 0, stream>>>(X, wq, wk, wv, wo, Xb);
  k_gemm_qkv<<<dim3(16, 16, 3), b256, 0, stream>>>(Xb, Wqb, Wkb, Wvb, Qm, Km, Vtm, pos);
  k_attn<<<1024, b256, 0, stream>>>(Qm, Km, Vtm, Om);
  k_gemm_wo_sk<<<dim3(16, 16, 2), b256, 0, stream>>>(Om, Wob, Pf);
  k_red<<<4096, b256, 0, stream>>>(Pf, out);
}

// Round 5
// 265.186 us; speedup vs baseline: 1.3205x; 1.3205x over previous
//
#include <hip/hip_runtime.h>

typedef unsigned short ushort_t;
typedef unsigned int uint32;
typedef __attribute__((ext_vector_type(8))) short short8;
typedef __attribute__((ext_vector_type(4))) float f32x4;
typedef __attribute__((ext_vector_type(2))) uint32 u32x2;

#define LDS_LOAD16(gptr, lptr)                                                             \
  __builtin_amdgcn_global_load_lds((const __attribute__((address_space(1))) uint32*)(gptr),\
                                   (__attribute__((address_space(3))) uint32*)(lptr),      \
                                   16, 0, 0)

__device__ __forceinline__ ushort_t f2b(float f) {
  uint32 u = __builtin_bit_cast(uint32, f);
  u += 0x7fffu + ((u >> 16) & 1u);   // RNE
  return (ushort_t)(u >> 16);
}
__device__ __forceinline__ uint32 pk2(float a, float b) {
  return (uint32)f2b(a) | ((uint32)f2b(b) << 16);
}

constexpr size_t E = (size_t)2048 * 2048;

// ---------------- fused fp32 -> bf16 convert (all 5 tensors) ----------------
__global__ __launch_bounds__(256) void k_cvt5(const float* __restrict__ a0, const float* __restrict__ a1,
                                              const float* __restrict__ a2, const float* __restrict__ a3,
                                              const float* __restrict__ a4, ushort_t* __restrict__ out) {
  const float* srcs[5] = {a0, a1, a2, a3, a4};
  const float* s = srcs[blockIdx.y];
  size_t i = ((size_t)blockIdx.x * 256 + threadIdx.x) * 4;
  float4 v = *(const float4*)(s + i);
  ushort4 o;
  o.x = f2b(v.x); o.y = f2b(v.y); o.z = f2b(v.z); o.w = f2b(v.w);
  *(ushort4*)(out + (size_t)blockIdx.y * E + i) = o;
}

// ===================== 3-buffer BK=32 rotating GEMM pipeline (R2-verified) =====================
#define SWZ3(r) (((r) >> 1) & 3)

#define STG32(srcA, srcB, dA, dB, ktile)                                        \
  do {                                                                          \
    const int koff_ = (ktile) * 32;                                             \
    _Pragma("unroll") for (int j2_ = 0; j2_ < 2; ++j2_) {                       \
      int c_ = tid + 256 * j2_;                                                 \
      int r_ = c_ >> 2, p_ = c_ & 3;                                            \
      int sc_ = (p_ ^ SWZ3(r_)) * 8;                                            \
      LDS_LOAD16((srcA) + (row0 + r_) * 2048 + koff_ + sc_, &(dA)[c_ * 8]);     \
      LDS_LOAD16((srcB) + (col0 + r_) * 2048 + koff_ + sc_, &(dB)[c_ * 8]);     \
    }                                                                           \
  } while (0)

// ---------------- fused QKV GEMM-BT, fused RoPE epilogue ----------------
__global__ __launch_bounds__(256, 3) void k_gemm_qkv(const ushort_t* __restrict__ A,
                                                     const ushort_t* __restrict__ B0,
                                                     const ushort_t* __restrict__ B1,
                                                     const ushort_t* __restrict__ B2,
                                                     ushort_t* __restrict__ Qm,
                                                     ushort_t* __restrict__ Km,
                                                     ushort_t* __restrict__ Vt,
                                                     const int* __restrict__ pos) {
  __shared__ ushort_t As[3][128 * 32];
  __shared__ ushort_t Bs[3][128 * 32];
  const int tid = threadIdx.x;
  const int lane = tid & 63, wave = tid >> 6;
  const int quad = lane >> 4, l16 = lane & 15;
  const int wm = wave >> 1, wn = wave & 1;
  const int z = blockIdx.z;
  const ushort_t* Bp = (z == 0) ? B0 : (z == 1) ? B1 : B2;
  const size_t row0 = (size_t)blockIdx.y * 128, col0 = (size_t)blockIdx.x * 128;

  int g[4];
#pragma unroll
  for (int j = 0; j < 4; ++j) g[j] = (j & 1) + ((j >> 1) << 2) + wn * 2;  // {0,1,4,5}/{2,3,6,7}

  f32x4 zero = {0.f, 0.f, 0.f, 0.f};
  f32x4 acc[4][4];
#pragma unroll
  for (int i = 0; i < 4; ++i)
#pragma unroll
    for (int j = 0; j < 4; ++j) acc[i][j] = zero;

#define QKV_FRAGS(CUR)                                                          \
    short8 a_[4], b_[4];                                                        \
    _Pragma("unroll") for (int i_ = 0; i_ < 4; ++i_) {                          \
      int ra_ = wm * 64 + i_ * 16 + l16;                                        \
      a_[i_] = *(const short8*)&As[CUR][(ra_ * 4 + (quad ^ SWZ3(ra_))) * 8];    \
    }                                                                           \
    _Pragma("unroll") for (int j_ = 0; j_ < 4; ++j_) {                          \
      int rb_ = g[j_] * 16 + l16;                                               \
      b_[j_] = *(const short8*)&Bs[CUR][(rb_ * 4 + (quad ^ SWZ3(rb_))) * 8];    \
    }                                                                           \
    _Pragma("unroll") for (int i_ = 0; i_ < 4; ++i_)                            \
      _Pragma("unroll") for (int j_ = 0; j_ < 4; ++j_)                          \
        acc[i_][j_] = __builtin_amdgcn_mfma_f32_16x16x32_bf16(a_[i_], b_[j_], acc[i_][j_], 0, 0, 0);

#define QKV_BODY(T, CUR, STG, SEN, VM)                                          \
  do {                                                                          \
    if (SEN) STG32(A, Bp, As[STG], Bs[STG], (T) + 2);                           \
    QKV_FRAGS(CUR)                                                              \
    asm volatile("s_waitcnt " VM ::: "memory");                                 \
    __builtin_amdgcn_s_barrier();                                               \
  } while (0)

  STG32(A, Bp, As[0], Bs[0], 0);
  STG32(A, Bp, As[1], Bs[1], 1);
  asm volatile("s_waitcnt vmcnt(4)" ::: "memory");
  __builtin_amdgcn_s_barrier();

  for (int tt = 0; tt < 60; tt += 3) {
    QKV_BODY(tt + 0, 0, 2, 1, "vmcnt(4)");
    QKV_BODY(tt + 1, 1, 0, 1, "vmcnt(4)");
    QKV_BODY(tt + 2, 2, 1, 1, "vmcnt(4)");
  }
  QKV_BODY(60, 0, 2, 1, "vmcnt(4)");
  QKV_BODY(61, 1, 0, 1, "vmcnt(4)");   // stages tile 63 into buf 0
  QKV_BODY(62, 2, 1, 0, "vmcnt(0)");   // no stage left; retire tile 63
  { QKV_FRAGS(0) }                     // t=63, no wait/barrier needed

  if (z < 2) {
    ushort_t* C = z ? Km : Qm;
    const float mul = z ? 1.0f : 0.08838834764831845f;  // fold 1/sqrt(128) into Q
#pragma unroll
    for (int i = 0; i < 4; ++i)
#pragma unroll
      for (int r = 0; r < 4; ++r) {
        size_t row = row0 + wm * 64 + i * 16 + quad * 4 + r;
        float pt = (float)pos[row];
        size_t rowoff = row * 2048 + col0;
#pragma unroll
        for (int j = 0; j < 2; ++j) {
          int f = g[j] * 16 + l16;   // f in [0,64)
          float ang = pt * __expf(-0.14391156831212787f * (float)f);
          float sn, cs;
          __sincosf(ang, &sn, &cs);
          cs *= mul; sn *= mul;
          float q0 = acc[i][j][r], q1 = acc[i][j + 2][r];
          C[rowoff + f]      = f2b(q0 * cs - q1 * sn);
          C[rowoff + f + 64] = f2b(q1 * cs + q0 * sn);
        }
      }
  } else {
#pragma unroll
    for (int i = 0; i < 4; ++i)
#pragma unroll
      for (int j = 0; j < 4; ++j) {
        size_t col = col0 + g[j] * 16 + l16;
        size_t rowb = row0 + wm * 64 + i * 16 + quad * 4;
        ushort4 ov;
        ov.x = f2b(acc[i][j][0]); ov.y = f2b(acc[i][j][1]);
        ov.z = f2b(acc[i][j][2]); ov.w = f2b(acc[i][j][3]);
        *(ushort4*)&Vt[col * 2048 + rowb] = ov;
      }
  }
}

// ---------------- flash attention: R2 structure + wave-private V LDS staging ----------------
// 64 q-rows/block, grid 512 (2 blocks/CU; register-pinned — R3 proved (256,4) spills).
// V slice (128d x 32keys = 8KB/wave) staged to LDS via global_load_lds issued at iter top
// BEFORE the K loads; the in-order vmcnt wait for kf retires V too, so V latency merges
// under K latency and PV pays ds_read (~20cyc) instead of an L2 round trip (~300cyc).
// Source pre-swizzled (chunk ^= (row>>1)&3), linear LDS dest (rule 21); read applies same XOR.
__global__ __launch_bounds__(256, 2) void k_attn(const ushort_t* __restrict__ Q,
                                                 const ushort_t* __restrict__ Kg,
                                                 const ushort_t* __restrict__ Vt,
                                                 ushort_t* __restrict__ O) {
  __shared__ uint32 smem[9216 + 256 + 8192];  // 69 KB: Qs 16K + Pbf 20K + Lred 1K + Vs 32K
  ushort_t* Qs  = (ushort_t*)smem;      // 64 x 128 bf16, swizzled: chunk c at c ^ (r&15)
  uint32*   Pbf = smem + 4096;          // 4 waves x 64 rows x 20 dwords (80 B stride)
  float*    Lred = (float*)(smem + 9216);  // [wave][qg][l16]
  ushort_t* Vs  = (ushort_t*)(smem + 9472); // 4 waves x 8KB V stage
  float*    Rbuf = (float*)smem;        // epilogue alias: [wave][16][132] = 8448 dw <= 9216

  const int tid = threadIdx.x;
  const int lane = tid & 63, wave = tid >> 6;
  const int quad = lane >> 4, l16 = lane & 15;
  const int bid = blockIdx.x;
  const int head = ((bid & 7) << 1) + ((bid >> 3) >> 5);
  const int qt = (bid >> 3) & 31;

#pragma unroll
  for (int j = 0; j < 4; ++j) {
    int s = tid + 256 * j;
    int r = s >> 4, p = s & 15;
    LDS_LOAD16(Q + (size_t)(qt * 64 + r) * 2048 + head * 128 + ((p ^ (r & 15)) * 8), &Qs[s * 8]);
  }
  __syncthreads();

  f32x4 zero = {0.f, 0.f, 0.f, 0.f};
  f32x4 oacc[4][8];
#pragma unroll
  for (int qg = 0; qg < 4; ++qg)
#pragma unroll
    for (int ns = 0; ns < 8; ++ns) oacc[qg][ns] = zero;
  float l_acc[4] = {0.f, 0.f, 0.f, 0.f};

  const ushort_t* Kbase = Kg + (size_t)head * 128;
  const ushort_t* Vbase = Vt + (size_t)head * 128 * 2048;
  uint32* pw = Pbf + wave * 1280;
  ushort_t* Vsw = Vs + wave * 4096;
  // V stage addressing: load l covers d-rows l*16+(lane>>2); key-chunk pre-swizzled so that
  // linear slot (r,c) holds chunk c ^ ((r>>1)&3)  [(r>>1)&3 == (lane>>3)&3, l*8 mod 4 = 0]
  const ushort_t* Vst = Vbase + (size_t)(lane >> 2) * 2048 + ((lane & 3) ^ ((lane >> 3) & 3)) * 8;
  const int vsw = (quad ^ ((l16 >> 1) & 3)) * 8;  // read-side swizzled chunk offset

  for (int it = 0; it < 16; ++it) {
    const int kb = it * 128 + wave * 32;

    // stage this wave's V slice first; kf loads issued after -> in-order vmcnt wait for kf
    // (inserted by compiler before QK MFMAs) retires these too: V latency hides under K's.
#pragma unroll
    for (int l = 0; l < 8; ++l)
      LDS_LOAD16(Vst + (size_t)l * 16 * 2048 + kb, &Vsw[(l * 64 + lane) * 8]);

    short8 kf[2][4];
#pragma unroll
    for (int kg = 0; kg < 2; ++kg)
#pragma unroll
      for (int kk = 0; kk < 4; ++kk)
        kf[kg][kk] = *(const short8*)&Kbase[(size_t)(kb + kg * 16 + l16) * 2048 + kk * 32 + quad * 8];

#pragma unroll
    for (int qg = 0; qg < 4; ++qg) {
      short8 qa[4];
#pragma unroll
      for (int kk = 0; kk < 4; ++kk)
        qa[kk] = *(const short8*)&Qs[((qg * 16 + l16) * 16 + ((kk * 4 + quad) ^ l16)) * 8];
      f32x4 s0 = zero, s1 = zero;
#pragma unroll
      for (int kk = 0; kk < 4; ++kk) {
        s0 = __builtin_amdgcn_mfma_f32_16x16x32_bf16(kf[0][kk], qa[kk], s0, 0, 0, 0);
        s1 = __builtin_amdgcn_mfma_f32_16x16x32_bf16(kf[1][kk], qa[kk], s1, 0, 0, 0);
      }
      float p00 = __expf(s0[0]), p01 = __expf(s0[1]);
      float p02 = __expf(s0[2]), p03 = __expf(s0[3]);
      float p10 = __expf(s1[0]), p11 = __expf(s1[1]);
      float p12 = __expf(s1[2]), p13 = __expf(s1[3]);
      l_acc[qg] += ((p00 + p01) + (p02 + p03)) + ((p10 + p11) + (p12 + p13));
      u32x2 w0, w1;
      w0[0] = pk2(p00, p01); w0[1] = pk2(p02, p03);
      w1[0] = pk2(p10, p11); w1[1] = pk2(p12, p13);
      int off = (qg * 16 + l16) * 20 + quad * 2;
      *(u32x2*)&pw[off]     = w0;
      *(u32x2*)&pw[off + 8] = w1;
    }

    short8 pb[4];
#pragma unroll
    for (int qg = 0; qg < 4; ++qg)
      pb[qg] = *(const short8*)&pw[(qg * 16 + l16) * 20 + quad * 4];  // B-op: [n=qrow][k=key]

    // V loads guaranteed landed before the LDS reads below (normally already retired by
    // the compiler's in-order kf wait, so this is ~free).
    asm volatile("s_waitcnt vmcnt(0)" ::: "memory");

#pragma unroll
    for (int ns = 0; ns < 8; ++ns) {
      const short8 vf = *(const short8*)&Vsw[(ns * 16 + l16) * 32 + vsw];
#pragma unroll
      for (int qg = 0; qg < 4; ++qg)
        oacc[qg][ns] = __builtin_amdgcn_mfma_f32_16x16x32_bf16(vf, pb[qg], oacc[qg][ns], 0, 0, 0);
    }

    // WAR fence: all Vs ds_reads complete before next iter's global_load_lds can rewrite Vs.
    asm volatile("s_waitcnt lgkmcnt(0)" ::: "memory");
  }

#pragma unroll
  for (int qg = 0; qg < 4; ++qg) {
    float l = l_acc[qg];
    l += __shfl_xor(l, 16, 64);
    l += __shfl_xor(l, 32, 64);
    l_acc[qg] = l;
  }
  if (quad == 0) {
#pragma unroll
    for (int qg = 0; qg < 4; ++qg) Lred[wave * 64 + qg * 16 + l16] = l_acc[qg];
  }

  const int tq = tid >> 4;
  const int td = (tid & 15) * 8;
  for (int qg = 0; qg < 4; ++qg) {
    __syncthreads();   // pass 0: Qs/Pbf dead, Lred visible; later: Rbuf free
#pragma unroll
    for (int ns = 0; ns < 8; ++ns)
      *(f32x4*)&Rbuf[(wave * 16 + l16) * 132 + ns * 16 + quad * 4] = oacc[qg][ns];
    __syncthreads();
    float lt = Lred[qg * 16 + tq] + Lred[64 + qg * 16 + tq] +
               Lred[128 + qg * 16 + tq] + Lred[192 + qg * 16 + tq];
    float inv = 1.0f / lt;
    f32x4 sA = zero, sB = zero;
#pragma unroll
    for (int w = 0; w < 4; ++w) {
      sA += *(const f32x4*)&Rbuf[(w * 16 + tq) * 132 + td];
      sB += *(const f32x4*)&Rbuf[(w * 16 + tq) * 132 + td + 4];
    }
    ushort4 o1, o2;
    o1.x = f2b(sA[0] * inv); o1.y = f2b(sA[1] * inv);
    o1.z = f2b(sA[2] * inv); o1.w = f2b(sA[3] * inv);
    o2.x = f2b(sB[0] * inv); o2.y = f2b(sB[1] * inv);
    o2.z = f2b(sB[2] * inv); o2.w = f2b(sB[3] * inv);
    size_t orow = (size_t)(qt * 64 + qg * 16 + tq) * 2048 + head * 128 + td;
    *(ushort4*)&O[orow] = o1;
    *(ushort4*)&O[orow + 4] = o2;
  }
}

// ---------------- Wo GEMM-BT, split-K=2: 128x128 tile, 3-buffer BK=32 pipeline ----------------
__global__ __launch_bounds__(256, 3) void k_gemm_wo_sk(const ushort_t* __restrict__ A,
                                                       const ushort_t* __restrict__ B,
                                                       float* __restrict__ P) {
  __shared__ ushort_t As[3][128 * 32];
  __shared__ ushort_t Bs[3][128 * 32];
  const int tid = threadIdx.x;
  const int lane = tid & 63, wave = tid >> 6;
  const int quad = lane >> 4, l16 = lane & 15;
  const int wm = wave >> 1, wn = wave & 1;
  const size_t row0 = (size_t)blockIdx.y * 128, col0 = (size_t)blockIdx.x * 128;
  const int k0 = blockIdx.z * 1024;
  float* Pz = P + (size_t)blockIdx.z * E;
  const ushort_t* Ak = A + k0;
  const ushort_t* Bk = B + k0;

  f32x4 zero = {0.f, 0.f, 0.f, 0.f};
  f32x4 acc[4][4];
#pragma unroll
  for (int i = 0; i < 4; ++i)
#pragma unroll
    for (int j = 0; j < 4; ++j) acc[i][j] = zero;

#define WO_FRAGS(CUR)                                                           \
    short8 a_[4], b_[4];                                                        \
    _Pragma("unroll") for (int i_ = 0; i_ < 4; ++i_) {                          \
      int ra_ = wm * 64 + i_ * 16 + l16;                                        \
      a_[i_] = *(const short8*)&As[CUR][(ra_ * 4 + (quad ^ SWZ3(ra_))) * 8];    \
    }                                                                           \
    _Pragma("unroll") for (int j_ = 0; j_ < 4; ++j_) {                          \
      int rb_ = wn * 64 + j_ * 16 + l16;                                        \
      b_[j_] = *(const short8*)&Bs[CUR][(rb_ * 4 + (quad ^ SWZ3(rb_))) * 8];    \
    }                                                                           \
    _Pragma("unroll") for (int i_ = 0; i_ < 4; ++i_)                            \
      _Pragma("unroll") for (int j_ = 0; j_ < 4; ++j_)                          \
        acc[i_][j_] = __builtin_amdgcn_mfma_f32_16x16x32_bf16(a_[i_], b_[j_], acc[i_][j_], 0, 0, 0);

#define WO_BODY(T, CUR, STG, SEN, VM)                                           \
  do {                                                                          \
    if (SEN) STG32(Ak, Bk, As[STG], Bs[STG], (T) + 2);                          \
    WO_FRAGS(CUR)                                                               \
    asm volatile("s_waitcnt " VM ::: "memory");                                 \
    __builtin_amdgcn_s_barrier();                                               \
  } while (0)

  STG32(Ak, Bk, As[0], Bs[0], 0);
  STG32(Ak, Bk, As[1], Bs[1], 1);
  asm volatile("s_waitcnt vmcnt(4)" ::: "memory");
  __builtin_amdgcn_s_barrier();

  for (int tt = 0; tt < 27; tt += 3) {
    WO_BODY(tt + 0, 0, 2, 1, "vmcnt(4)");
    WO_BODY(tt + 1, 1, 0, 1, "vmcnt(4)");
    WO_BODY(tt + 2, 2, 1, 1, "vmcnt(4)");
  }
  WO_BODY(27, 0, 2, 1, "vmcnt(4)");
  WO_BODY(28, 1, 0, 1, "vmcnt(4)");
  WO_BODY(29, 2, 1, 1, "vmcnt(4)");    // stages tile 31 into buf 1
  WO_BODY(30, 0, 2, 0, "vmcnt(0)");    // no stage left; retire tile 31
  { WO_FRAGS(1) }                      // t=31, no wait/barrier needed

#pragma unroll
  for (int i = 0; i < 4; ++i)
#pragma unroll
    for (int j = 0; j < 4; ++j)
#pragma unroll
      for (int r = 0; r < 4; ++r) {
        size_t row = row0 + wm * 64 + i * 16 + quad * 4 + r;
        size_t col = col0 + wn * 64 + j * 16 + l16;
        Pz[row * 2048 + col] = acc[i][j][r];
      }
}

// ---------------- split-K reduce: out = P0 + P1 (fp32) ----------------
__global__ __launch_bounds__(256) void k_red(const float* __restrict__ P, float* __restrict__ out) {
  size_t i = ((size_t)blockIdx.x * 256 + threadIdx.x) * 4;
  f32x4 a = *(const f32x4*)(P + i);
  f32x4 b = *(const f32x4*)(P + E + i);
  *(f32x4*)(out + i) = a + b;
}

extern "C" void kernel_launch(void* const* d_in, const int* in_sizes, int n_in,
                              void* d_out, int out_size, void* d_ws, size_t ws_size,
                              hipStream_t stream) {
  const float* X  = (const float*)d_in[0];
  const float* wq = (const float*)d_in[1];
  const float* wk = (const float*)d_in[2];
  const float* wv = (const float*)d_in[3];
  const float* wo = (const float*)d_in[4];
  const int*  pos = (const int*)d_in[5];
  float* out = (float*)d_out;

  if (ws_size < 9 * E * sizeof(ushort_t)) return;  // need 72 MB scratch

  ushort_t* Xb  = (ushort_t*)d_ws;
  ushort_t* Wqb = Xb + E;
  ushort_t* Wkb = Xb + 2 * E;
  ushort_t* Wvb = Xb + 3 * E;
  ushort_t* Wob = Xb + 4 * E;
  ushort_t* Qm  = Xb + 5 * E;
  ushort_t* Km  = Xb + 6 * E;
  ushort_t* Vtm = Xb + 7 * E;
  ushort_t* Om  = Xb + 8 * E;
  // After k_attn, Xb..Wvb (4E ushorts = 32 MB) are dead: reuse as 2x fp32 partial planes.
  float* Pf = (float*)Xb;   // P0 = [0,E) floats, P1 = [E,2E) floats

  dim3 b256(256);
  k_cvt5<<<dim3(4096, 5), b256, 0, stream>>>(X, wq, wk, wv, wo, Xb);
  k_gemm_qkv<<<dim3(16, 16, 3), b256, 0, stream>>>(Xb, Wqb, Wkb, Wvb, Qm, Km, Vtm, pos);
  k_attn<<<512, b256, 0, stream>>>(Qm, Km, Vtm, Om);
  k_gemm_wo_sk<<<dim3(16, 16, 2), b256, 0, stream>>>(Om, Wob, Pf);
  k_red<<<4096, b256, 0, stream>>>(Pf, out);
}